// Round 9
// baseline (166.817 us; speedup 1.0000x reference)
//
#include <hip/hip_runtime.h>
#include <hip/hip_fp16.h>

// CTC-like forward scan. R20 = R19 wings in SEPARATE BLOCKS + tiny join kernel.
//   out = e_sl^T B_T...B_1 e_0,  B_t lower-bidiagonal (diag S_t, sub V_t).
// R19 measured: 2 wings co-resident on one CU run at 131 cy/step vs 109 solo
// (VALUBusy 7.37/12.5 = 59% vs 74% solo; busy-cy/step unchanged ~78) =>
// +20% pure co-residency stall (shared LDS pipe for at-use ds_reads +
// global_load_lds staging). The wings are independent until the junction, so:
// 128 blocks x 64 threads (1 wave/CU on 256 CUs), wings write garr halves +
// log-scales to workspace, and a third ~3us kernel does the 513-entry LSE
// junction. Stream ordering = cross-block sync (kernel boundary is a
// device-scope release; XCD-safe). Wing math BYTE-IDENTICAL to R19 (passed,
// absmax 0.0): G-space recurrence, f16 W via v_perm + forced v_fma_mix_f32,
// renorm every 8 steps, down-only alignment, DPP boundary pass, logs = sum x4.
// Validation bit: scan dispatch ~93-98us (109 cy/step restored). If it stays
// ~112, co-residency theory is wrong -> re-audit.

#define TT 4096
#define BB 64
#define PP 512
#define LN2F 0.69314718055994531f
#define LOG2E 1.44269504088896341f
#define JSTRIDE 1040   // per-batch floats in junction buffer (64B-aligned)

typedef unsigned u32x4 __attribute__((ext_vector_type(4)));

__device__ __forceinline__ unsigned f16_bits(float f) {
    return (unsigned)__half_as_ushort(__float2half(f));   // v_cvt_f16_f32, RNE
}

// prepass: x[t][b][5] -> xq[b*4096+t] = {f16W0|W1, f16W2|W3, f32 x4, 0}
__global__ __launch_bounds__(256, 1)
void ctc_prepass(const float* __restrict__ x, u32x4* __restrict__ xq) {
    int j = blockIdx.x * 256 + threadIdx.x;
    int b = j >> 12, t = j & 4095;
    const float* r = x + (size_t)(t * 64 + b) * 5;
    float x0 = r[0], x1 = r[1], x2 = r[2], x3 = r[3], x4 = r[4];
    float w0 = fminf(__expf(x0 - x4), 65000.0f);   // clamp: f16 inf insurance
    float w1 = fminf(__expf(x1 - x4), 65000.0f);
    float w2 = fminf(__expf(x2 - x4), 65000.0f);
    float w3 = fminf(__expf(x3 - x4), 65000.0f);
    u32x4 o;
    o[0] = f16_bits(w0) | (f16_bits(w1) << 16);
    o[1] = f16_bits(w2) | (f16_bits(w3) << 16);
    o[2] = __float_as_uint(x4);
    o[3] = 0u;
    xq[j] = o;
}

__device__ __forceinline__ void gload_lds16(const void* g, void* l) {
    auto gp = (const __attribute__((address_space(1))) void*)(uintptr_t)g;
    auto lp = (__attribute__((address_space(3))) void*)(uintptr_t)l;
    __builtin_amdgcn_global_load_lds(gp, lp, 16, 0, 0);
}

// lane n <- lane n-1 (wave_shr:1); lane 0 keeps old (overridden).
__device__ __forceinline__ int shl1w_i(int s) {
    return __builtin_amdgcn_update_dpp(s, s, 0x138, 0xF, 0xF, false);
}
__device__ __forceinline__ float shl1w_f(float s) {
    return __int_as_float(shl1w_i(__float_as_int(s)));
}
// lane n <- lane n+1 (wave_shl:1); lane 63 keeps old (overridden).
__device__ __forceinline__ int sh1up_i(int s) {
    return __builtin_amdgcn_update_dpp(s, s, 0x130, 0xF, 0xF, false);
}
__device__ __forceinline__ float sh1up_f(float s) {
    return __int_as_float(sh1up_i(__float_as_int(s)));
}

// acc += s * f16(lo/hi of p)   -- one v_fma_mix_f32, f16 source in S1
#define FMA_MIX_LO(acc, s, p)                                              \
    asm("v_fma_mix_f32 %0, %1, %2, %0 op_sel:[0,0,0] op_sel_hi:[0,1,0]"    \
        : "+v"(acc) : "v"(s), "v"(p))
#define FMA_MIX_HI(acc, s, p)                                              \
    asm("v_fma_mix_f32 %0, %1, %2, %0 op_sel:[0,1,0] op_sel_hi:[0,1,0]"    \
        : "+v"(acc) : "v"(s), "v"(p))

__global__ __launch_bounds__(64, 1)
void ctc_scan(const u32x4* __restrict__ xq, const int* __restrict__ seqs,
              const int* __restrict__ seqlens, float* __restrict__ jbuf) {
    __shared__ __align__(16) u32x4 ring[512];      // 8 KB: 8 chunks x 64 rows

    const int b = blockIdx.x >> 1;                 // batch
    const int w = blockIdx.x & 1;                  // 0 = fwd, 1 = bwd
    const int l = threadIdx.x;                     // 0..63
    const bool lane0 = (l == 0);
    const bool lane63 = (l == 63);
    float* const jb = jbuf + (size_t)b * JSTRIDE;  // [0..512]=F, [520..1032]=B,
                                                   // [1036]=lgSF, [1037]=lgSB

    // per-lane v_perm byte controls -- identical for fwd and bwd wings.
    unsigned ctrl[4];
#pragma unroll
    for (int k = 0; k < 4; ++k) {
        unsigned i0 = (unsigned)seqs[b * PP + 8 * l + 2 * k];
        unsigned i1 = (unsigned)seqs[b * PP + 8 * l + 2 * k + 1];
        ctrl[k] = (2 * i0) | ((2 * i0 + 1) << 8) | ((2 * i1) << 16) | ((2 * i1 + 1) << 24);
    }

    const u32x4* gsrc = xq + (size_t)b * 4096;     // row t at gsrc[t]

    float F[8];
    int M = 0;
    float logs = 0.0f;

    if (w == 0) {
        // ================= FORWARD: rows 0..2047 (verified R14 body) ======
#pragma unroll
        for (int i = 0; i < 8; ++i) F[i] = 0.0f;
#pragma unroll
        for (int c0 = 0; c0 < 4; ++c0)
            gload_lds16(gsrc + c0 * 64 + l, &ring[c0 * 64 + l]);
        asm volatile("s_waitcnt vmcnt(3)" ::: "memory");

        u32x4 wA[8], wB[8];
#pragma unroll
        for (int i = 0; i < 8; ++i) wA[i] = ring[i];
        int nrow = 8;

        auto fwin = [&](u32x4 (&cur)[8], u32x4 (&nxt)[8]) {
            const int rb = nrow & 511;
            nrow += 8;
#pragma unroll
            for (int i = 0; i < 8; ++i) nxt[i] = ring[rb + i];
            asm volatile("" ::: "memory");

            float m = F[0];
#pragma unroll
            for (int i = 1; i < 8; ++i) m = fmaxf(m, F[i]);
            int e2 = ((__float_as_int(m) >> 23) & 0xFF) - 127;
            e2 = (m > 0.0f) ? e2 : 0;
            const int Mp = M + e2;
            const int Mlp = shl1w_i(Mp);
            int dl = (lane0 ? 0 : Mlp) - Mp;
            int dlc = dl > 0 ? dl : 0;
            const int Mnew = Mp + dlc;
            const int sh = Mnew - M;
#pragma unroll
            for (int i = 0; i < 8; ++i) F[i] = ldexpf(F[i], -sh);
            M = Mnew;
            int dn = Mlp - M; dn = dn > 0 ? 0 : dn;
            const float sAx  = lane0 ? 0.0f : ldexpf(1.0f, dn);
            const float cfin = lane0 ? ldexpf(1.0f, -M) : 0.0f;

#pragma unroll
            for (int u = 0; u < 8; ++u) {
                const u32x4 row = cur[u];
                logs += __uint_as_float(row[2]);
                unsigned p0 = __builtin_amdgcn_perm(row[1], row[0], ctrl[0]);
                unsigned p1 = __builtin_amdgcn_perm(row[1], row[0], ctrl[1]);
                unsigned p2 = __builtin_amdgcn_perm(row[1], row[0], ctrl[2]);
                unsigned p3 = __builtin_amdgcn_perm(row[1], row[0], ctrl[3]);
                const float Flr = shl1w_f(F[7]);
                const float fin = fmaf(Flr, sAx, cfin);
                FMA_MIX_HI(F[7], F[6], p3);
                FMA_MIX_LO(F[6], F[5], p3);
                FMA_MIX_HI(F[5], F[4], p2);
                FMA_MIX_LO(F[4], F[3], p2);
                FMA_MIX_HI(F[3], F[2], p1);
                FMA_MIX_LO(F[2], F[1], p1);
                FMA_MIX_HI(F[1], F[0], p0);
                FMA_MIX_LO(F[0], fin,  p0);
            }
        };

#pragma unroll 1
        for (int c = 0; c < 32; ++c) {
            int cs = (c + 4 > 31) ? 31 : (c + 4);
            gload_lds16(gsrc + cs * 64 + l, &ring[((c + 4) & 7) * 64 + l]);
            asm volatile("s_waitcnt vmcnt(3)" ::: "memory");
#pragma unroll 1
            for (int pr = 0; pr < 4; ++pr) { fwin(wA, wB); fwin(wB, wA); }
        }

        // junction write: jb[p] = log2(gf[p]) + Mf ; jb[0] = 0 (G[0]=1)
#pragma unroll
        for (int i = 0; i < 8; ++i) {
            float v = fmaxf(F[i] * 16777216.0f, 1e-38f);
            jb[8 * l + 1 + i] = __log2f(v) - 24.0f + (float)M;
        }
        if (lane0) { jb[0] = 0.0f; jb[1036] = logs * LOG2E; }
    } else {
        // ================= BACKWARD: rows 4095..2048 (mirror) =============
        const int sl = seqlens[b];
        const bool b512 = (sl == PP);
#pragma unroll
        for (int k = 0; k < 8; ++k) F[k] = (8 * l + k == sl) ? 1.0f : 0.0f;
#pragma unroll
        for (int c0 = 0; c0 < 4; ++c0) {
            const int cp = 63 - c0;
            gload_lds16(gsrc + cp * 64 + l, &ring[(cp & 7) * 64 + l]);
        }
        asm volatile("s_waitcnt vmcnt(3)" ::: "memory");   // chunk 63 resident

        u32x4 wA[8], wB[8];
#pragma unroll
        for (int i = 0; i < 8; ++i) wA[i] = ring[511 - i];  // rows 4095..4088
        int nbase = 4095 - 8;                       // top row of next window

        auto bwin = [&](u32x4 (&cur)[8], u32x4 (&nxt)[8]) {
            const int rb = nbase & 511;
            nbase -= 8;
#pragma unroll
            for (int i = 0; i < 8; ++i) nxt[i] = ring[(rb - i) & 511];
            asm volatile("" ::: "memory");

            float m = F[0];
#pragma unroll
            for (int i = 1; i < 8; ++i) m = fmaxf(m, F[i]);
            int e2 = ((__float_as_int(m) >> 23) & 0xFF) - 127;
            e2 = (m > 0.0f) ? e2 : 0;
            const int Mp = M + e2;
            const int Mup = sh1up_i(Mp);            // lane l+1's frame
            int nb = lane63 ? (b512 ? 0 : -1048576) : Mup;
            int dl = nb - Mp;
            int dlc = dl > 0 ? dl : 0;
            const int Mnew = Mp + dlc;
            const int sh = Mnew - M;
#pragma unroll
            for (int i = 0; i < 8; ++i) F[i] = ldexpf(F[i], -sh);
            M = Mnew;
            int dn = Mup - M; dn = dn > 0 ? 0 : dn;
            const float sAx  = lane63 ? 0.0f : ldexpf(1.0f, dn);
            const float cfin = (lane63 && b512) ? ldexpf(1.0f, -M) : 0.0f;

#pragma unroll
            for (int u = 0; u < 8; ++u) {
                const u32x4 row = cur[u];
                logs += __uint_as_float(row[2]);
                unsigned p0 = __builtin_amdgcn_perm(row[1], row[0], ctrl[0]);
                unsigned p1 = __builtin_amdgcn_perm(row[1], row[0], ctrl[1]);
                unsigned p2 = __builtin_amdgcn_perm(row[1], row[0], ctrl[2]);
                unsigned p3 = __builtin_amdgcn_perm(row[1], row[0], ctrl[3]);
                const float Bur = sh1up_f(F[0]);    // lane n <- n+1's gb-bottom
                const float fin = fmaf(Bur, sAx, cfin);
                // gb[p] += W[p+1]*gb[p+1], ascending (old upper values)
                FMA_MIX_LO(F[0], F[1], p0);
                FMA_MIX_HI(F[1], F[2], p0);
                FMA_MIX_LO(F[2], F[3], p1);
                FMA_MIX_HI(F[3], F[4], p1);
                FMA_MIX_LO(F[4], F[5], p2);
                FMA_MIX_HI(F[5], F[6], p2);
                FMA_MIX_LO(F[6], F[7], p3);
                FMA_MIX_HI(F[7], fin,  p3);
            }
        };

#pragma unroll 1
        for (int c = 0; c < 32; ++c) {
            int cp = 59 - c; cp = cp < 32 ? 32 : cp;
            gload_lds16(gsrc + cp * 64 + l, &ring[(cp & 7) * 64 + l]);
            asm volatile("s_waitcnt vmcnt(3)" ::: "memory");
#pragma unroll 1
            for (int pr = 0; pr < 4; ++pr) { bwin(wA, wB); bwin(wB, wA); }
        }

        // junction write: jb[520+p] = log2(gb[p]) + Mb ; [520+512] = [sl==512]
#pragma unroll
        for (int k = 0; k < 8; ++k) {
            float v = fmaxf(F[k] * 16777216.0f, 1e-38f);
            jb[520 + 8 * l + k] = __log2f(v) - 24.0f + (float)M;
        }
        if (lane0) { jb[520 + PP] = b512 ? 0.0f : -1e30f; jb[1037] = logs * LOG2E; }
    }
}

// junction: log2(out) = LSE2_p(jF[p]+jB[p]) + lgSF + lgSB
__global__ __launch_bounds__(64, 1)
void ctc_join(const float* __restrict__ jbuf, float* __restrict__ out) {
    const int b = blockIdx.x;
    const int l = threadIdx.x;
    const float* jb = jbuf + (size_t)b * JSTRIDE;

    float smax = -3.0e38f;
#pragma unroll
    for (int k = 0; k < 9; ++k) {
        const int p = l + (k << 6);
        if (p <= PP) smax = fmaxf(smax, jb[p] + jb[520 + p]);
    }
#pragma unroll
    for (int off = 32; off >= 1; off >>= 1)
        smax = fmaxf(smax, __shfl_xor(smax, off));
    float ssum = 0.0f;
#pragma unroll
    for (int k = 0; k < 9; ++k) {
        const int p = l + (k << 6);
        if (p <= PP) ssum += exp2f((jb[p] + jb[520 + p]) - smax);
    }
#pragma unroll
    for (int off = 32; off >= 1; off >>= 1)
        ssum += __shfl_xor(ssum, off);
    if (l == 0)
        out[b] = -((smax + __log2f(ssum)) + jb[1036] + jb[1037]) * LN2F / (float)TT;
}

extern "C" void kernel_launch(void* const* d_in, const int* in_sizes, int n_in,
                              void* d_out, int out_size, void* d_ws, size_t ws_size,
                              hipStream_t stream) {
    const float* x       = (const float*)d_in[0];
    const int*   seqs    = (const int*)d_in[1];
    const int*   seqlens = (const int*)d_in[2];
    float*       out     = (float*)d_out;
    u32x4*       xq      = (u32x4*)d_ws;                        // 4 MB
    float*       jbuf    = (float*)((char*)d_ws + (4u << 20));  // 64*1040 f32

    ctc_prepass<<<(TT * BB) / 256, 256, 0, stream>>>(x, xq);
    ctc_scan<<<BB * 2, 64, 0, stream>>>(xq, seqs, seqlens, jbuf);
    ctc_join<<<BB, 64, 0, stream>>>(jbuf, out);
}